// Round 1
// baseline (7486.314 us; speedup 1.0000x reference)
//
#include <hip/hip_runtime.h>

#define NN 100000      // nodes
#define NE 1600000     // edges
#define HD 128         // hidden dim

// ---------------------------------------------------------------------------
// Edge aggregation: agg[dst[e]] += x[src[e]]  (atomic scatter-add, fp32)
// ---------------------------------------------------------------------------
template<int F>
__global__ __launch_bounds__(256)
void k_agg(const float* __restrict__ x, const int* __restrict__ src,
           const int* __restrict__ dst, float* __restrict__ agg) {
    constexpr int F4 = F / 4;
    long long idx = (long long)blockIdx.x * 256 + threadIdx.x;
    constexpr long long total = (long long)NE * F4;
    if (idx >= total) return;
    int e = (int)(idx / F4);
    int c = (int)(idx % F4);
    int s = src[e], d = dst[e];
    float4 v = reinterpret_cast<const float4*>(x)[(long long)s * F4 + c];
    float* o = agg + (long long)d * F + c * 4;
    atomicAdd(o + 0, v.x);
    atomicAdd(o + 1, v.y);
    atomicAdd(o + 2, v.z);
    atomicAdd(o + 3, v.w);
}

// ---------------------------------------------------------------------------
// GEMM: C[N x 128] = Aop(A) @ W[K x 128] + bias, with fused prolog/epilog.
// MODE 0: Aop = (1+eps)*A + agg          C = acc + bias        (GIN lin1)
// MODE 1: Aop = relu(af*A + bf)          C = relu(acc + bias)  (BN+relu fused, lin2 + outer relu)
// MODE 2: Aop = A                        C = relu(acc + bias)  (head lin1)
// Tile: 128 rows x 128 cols per block, 256 threads, 8x8 accum per thread.
// ---------------------------------------------------------------------------
template<int K, int MODE>
__global__ __launch_bounds__(256)
void k_gemm(const float* __restrict__ A,
            const float* __restrict__ aux0,   // agg (MODE0) or af (MODE1)
            const float* __restrict__ aux1,   // eps ptr (MODE0) or bf (MODE1)
            const float* __restrict__ W,
            const float* __restrict__ bias,
            float* __restrict__ C) {
    constexpr int BM = 128, BN = 128, KC = 32;
    __shared__ float As[KC][BM + 4];   // transposed: As[k][row]
    __shared__ float Bs[KC][BN];

    const int t = threadIdx.x;
    const int rbase = blockIdx.x * BM;
    const int tx = t & 15, ty = t >> 4;
    const int col0 = tx * 8, row0 = ty * 8;

    float acc[8][8];
    #pragma unroll
    for (int i = 0; i < 8; ++i)
        #pragma unroll
        for (int j = 0; j < 8; ++j) acc[i][j] = 0.f;

    float epsv = 0.f;
    if (MODE == 0) epsv = 1.0f + aux1[0];

    for (int kb = 0; kb < K; kb += KC) {
        // --- load A chunk (BM x KC) -> LDS transposed ---
        #pragma unroll
        for (int i = 0; i < 4; ++i) {
            int q   = t * 4 + i;        // 0..1023 float4 slots
            int row = q >> 3;           // 0..127
            int kq  = q & 7;            // float4 index inside K-chunk
            int grow = rbase + row;
            float4 v = make_float4(0.f, 0.f, 0.f, 0.f);
            if (grow < NN) {
                long long gidx = (long long)grow * K + kb + kq * 4;
                v = *reinterpret_cast<const float4*>(A + gidx);
                if (MODE == 0) {
                    float4 g = *reinterpret_cast<const float4*>(aux0 + gidx);
                    v.x = fmaf(epsv, v.x, g.x);
                    v.y = fmaf(epsv, v.y, g.y);
                    v.z = fmaf(epsv, v.z, g.z);
                    v.w = fmaf(epsv, v.w, g.w);
                } else if (MODE == 1) {
                    int kk = kb + kq * 4;
                    float4 a4 = *reinterpret_cast<const float4*>(aux0 + kk);
                    float4 b4 = *reinterpret_cast<const float4*>(aux1 + kk);
                    v.x = fmaxf(fmaf(a4.x, v.x, b4.x), 0.f);
                    v.y = fmaxf(fmaf(a4.y, v.y, b4.y), 0.f);
                    v.z = fmaxf(fmaf(a4.z, v.z, b4.z), 0.f);
                    v.w = fmaxf(fmaf(a4.w, v.w, b4.w), 0.f);
                }
            }
            As[kq * 4 + 0][row] = v.x;
            As[kq * 4 + 1][row] = v.y;
            As[kq * 4 + 2][row] = v.z;
            As[kq * 4 + 3][row] = v.w;
        }
        // --- load W chunk (KC x BN) -> LDS ---
        #pragma unroll
        for (int i = 0; i < 4; ++i) {
            int q  = t * 4 + i;         // 0..1023
            int k  = q >> 5;            // 0..31
            int c4 = q & 31;
            float4 w = *reinterpret_cast<const float4*>(W + (long long)(kb + k) * BN + c4 * 4);
            *reinterpret_cast<float4*>(&Bs[k][c4 * 4]) = w;
        }
        __syncthreads();

        #pragma unroll
        for (int k = 0; k < KC; ++k) {
            float a[8], b[8];
            *reinterpret_cast<float4*>(&a[0]) = *reinterpret_cast<const float4*>(&As[k][row0]);
            *reinterpret_cast<float4*>(&a[4]) = *reinterpret_cast<const float4*>(&As[k][row0 + 4]);
            *reinterpret_cast<float4*>(&b[0]) = *reinterpret_cast<const float4*>(&Bs[k][col0]);
            *reinterpret_cast<float4*>(&b[4]) = *reinterpret_cast<const float4*>(&Bs[k][col0 + 4]);
            #pragma unroll
            for (int i = 0; i < 8; ++i)
                #pragma unroll
                for (int j = 0; j < 8; ++j)
                    acc[i][j] = fmaf(a[i], b[j], acc[i][j]);
        }
        __syncthreads();
    }

    // --- epilogue ---
    float bv[8];
    *reinterpret_cast<float4*>(&bv[0]) = *reinterpret_cast<const float4*>(bias + col0);
    *reinterpret_cast<float4*>(&bv[4]) = *reinterpret_cast<const float4*>(bias + col0 + 4);
    #pragma unroll
    for (int i = 0; i < 8; ++i) {
        int grow = rbase + row0 + i;
        if (grow < NN) {
            float o[8];
            #pragma unroll
            for (int j = 0; j < 8; ++j) {
                float v = acc[i][j] + bv[j];
                if (MODE != 0) v = fmaxf(v, 0.f);
                o[j] = v;
            }
            *reinterpret_cast<float4*>(C + (long long)grow * HD + col0)     = *reinterpret_cast<float4*>(&o[0]);
            *reinterpret_cast<float4*>(C + (long long)grow * HD + col0 + 4) = *reinterpret_cast<float4*>(&o[4]);
        }
    }
}

// ---------------------------------------------------------------------------
// Column stats (sum, sumsq) over N rows of y[N x 128], double accumulation.
// block = 128 threads (one col each), grid covers row chunks.
// ---------------------------------------------------------------------------
__global__ __launch_bounds__(128)
void k_colstats(const float* __restrict__ y, double* __restrict__ dsum,
                double* __restrict__ dsq, int rows_per_block) {
    int c  = threadIdx.x;
    int r0 = blockIdx.x * rows_per_block;
    int r1 = r0 + rows_per_block;
    if (r1 > NN) r1 = NN;
    double s = 0.0, sq = 0.0;
    for (int r = r0; r < r1; ++r) {
        float v = y[(long long)r * HD + c];
        s  += (double)v;
        sq += (double)v * (double)v;
    }
    atomicAdd(&dsum[c], s);
    atomicAdd(&dsq[c], sq);
}

__global__ __launch_bounds__(128)
void k_bnfin(const double* __restrict__ dsum, const double* __restrict__ dsq,
             const float* __restrict__ g, const float* __restrict__ be,
             float* __restrict__ af, float* __restrict__ bf) {
    int c = threadIdx.x;
    double mu  = dsum[c] / (double)NN;
    double var = dsq[c] / (double)NN - mu * mu;
    double a   = (double)g[c] / sqrt(var + 1e-5);
    af[c] = (float)a;
    bf[c] = be[c] - (float)(mu * a);
}

// ---------------------------------------------------------------------------
// Head lin2: out[N x 2] = x[N x 128] @ w[128 x 2] + b
// ---------------------------------------------------------------------------
__global__ __launch_bounds__(256)
void k_head2(const float* __restrict__ x, const float* __restrict__ w,
             const float* __restrict__ b, float* __restrict__ out) {
    __shared__ float ws[256];
    if (threadIdx.x < 256) ws[threadIdx.x] = w[threadIdx.x];
    __syncthreads();
    int r = blockIdx.x * blockDim.x + threadIdx.x;
    if (r >= NN) return;
    float a0 = b[0], a1 = b[1];
    const float4* xr = reinterpret_cast<const float4*>(x + (long long)r * HD);
    #pragma unroll
    for (int k4 = 0; k4 < 32; ++k4) {
        float4 v = xr[k4];
        int k = k4 * 4;
        a0 = fmaf(v.x, ws[(k + 0) * 2], a0);
        a0 = fmaf(v.y, ws[(k + 1) * 2], a0);
        a0 = fmaf(v.z, ws[(k + 2) * 2], a0);
        a0 = fmaf(v.w, ws[(k + 3) * 2], a0);
        a1 = fmaf(v.x, ws[(k + 0) * 2 + 1], a1);
        a1 = fmaf(v.y, ws[(k + 1) * 2 + 1], a1);
        a1 = fmaf(v.z, ws[(k + 2) * 2 + 1], a1);
        a1 = fmaf(v.w, ws[(k + 3) * 2 + 1], a1);
    }
    out[r * 2 + 0] = a0;
    out[r * 2 + 1] = a1;
}

// ---------------------------------------------------------------------------
extern "C" void kernel_launch(void* const* d_in, const int* in_sizes, int n_in,
                              void* d_out, int out_size, void* d_ws, size_t ws_size,
                              hipStream_t stream) {
    const float* x  = (const float*)d_in[0];
    const int*   ei = (const int*)d_in[1];
    const int* src = ei;
    const int* dst = ei + NE;

    // per-layer params: base index 2 + 7*l
    auto P = [&](int i) { return (const float*)d_in[i]; };

    const size_t BUF = (size_t)NN * HD * sizeof(float);   // 51.2 MB
    char* ws = (char*)d_ws;
    float* agg  = (float*)(ws);
    float* ybuf = (float*)(ws + BUF);
    float* hA   = (float*)(ws + 2 * BUF);
    float* hB   = (float*)(ws + 3 * BUF);
    char*  sb   = ws + 4 * BUF;
    double* dsum = (double*)(sb);
    double* dsq  = (double*)(sb + 1024);
    float*  af   = (float*)(sb + 2048);
    float*  bf   = (float*)(sb + 2048 + 512);

    const int GEMM_GRID = (NN + 127) / 128;   // 782
    const int STAT_GRID = 512;
    const int STAT_ROWS = (NN + STAT_GRID - 1) / STAT_GRID;  // 196

    auto bn = [&](const float* g, const float* be) {
        hipMemsetAsync(dsum, 0, 2048, stream);
        k_colstats<<<STAT_GRID, 128, 0, stream>>>(ybuf, dsum, dsq, STAT_ROWS);
        k_bnfin<<<1, 128, 0, stream>>>(dsum, dsq, g, be, af, bf);
    };

    // ---- layer 0 (K = 64) ----
    hipMemsetAsync(agg, 0, (size_t)NN * 64 * sizeof(float), stream);
    {
        long long total = (long long)NE * (64 / 4);
        k_agg<64><<<(int)((total + 255) / 256), 256, 0, stream>>>(x, src, dst, agg);
    }
    k_gemm<64, 0><<<GEMM_GRID, 256, 0, stream>>>(x, agg, P(8), P(2), P(3), ybuf);
    bn(P(4), P(5));
    k_gemm<128, 1><<<GEMM_GRID, 256, 0, stream>>>(ybuf, af, bf, P(6), P(7), hA);

    // ---- layer 1 (K = 128) ----
    hipMemsetAsync(agg, 0, BUF, stream);
    {
        long long total = (long long)NE * (128 / 4);
        k_agg<128><<<(int)((total + 255) / 256), 256, 0, stream>>>(hA, src, dst, agg);
    }
    k_gemm<128, 0><<<GEMM_GRID, 256, 0, stream>>>(hA, agg, P(15), P(9), P(10), ybuf);
    bn(P(11), P(12));
    k_gemm<128, 1><<<GEMM_GRID, 256, 0, stream>>>(ybuf, af, bf, P(13), P(14), hB);

    // ---- layer 2 (K = 128) ----
    hipMemsetAsync(agg, 0, BUF, stream);
    {
        long long total = (long long)NE * (128 / 4);
        k_agg<128><<<(int)((total + 255) / 256), 256, 0, stream>>>(hB, src, dst, agg);
    }
    k_gemm<128, 0><<<GEMM_GRID, 256, 0, stream>>>(hB, agg, P(22), P(16), P(17), ybuf);
    bn(P(18), P(19));
    k_gemm<128, 1><<<GEMM_GRID, 256, 0, stream>>>(ybuf, af, bf, P(20), P(21), hA);

    // ---- head ----
    k_gemm<128, 2><<<GEMM_GRID, 256, 0, stream>>>(hA, nullptr, nullptr, P(23), P(24), ybuf);
    k_head2<<<(NN + 255) / 256, 256, 0, stream>>>(ybuf, P(25), P(26), (float*)d_out);
}

// Round 3
// 1204.910 us; speedup vs baseline: 6.2132x; 6.2132x over previous
//
#include <hip/hip_runtime.h>

#define NN 100000      // nodes
#define NE 1600000     // edges
#define HD 128         // hidden dim
#define NB1 391        // ceil(NN/256) scan blocks

// ===========================================================================
// CSR build: degree histogram -> exclusive scan (rowptr) -> scatter src by dst
// ===========================================================================
__global__ __launch_bounds__(256)
void k_hist(const int* __restrict__ dst, int* __restrict__ degree) {
    int e = blockIdx.x * 256 + threadIdx.x;
    if (e < NE) atomicAdd(degree + dst[e], 1);
}

__global__ __launch_bounds__(256)
void k_scan_blk(const int* __restrict__ degree, int* __restrict__ incl,
                int* __restrict__ bsum) {
    __shared__ int s[256];
    int t = threadIdx.x;
    int i = blockIdx.x * 256 + t;
    int v = (i < NN) ? degree[i] : 0;
    s[t] = v;
    __syncthreads();
    #pragma unroll
    for (int off = 1; off < 256; off <<= 1) {
        int tmp = (t >= off) ? s[t - off] : 0;
        __syncthreads();
        s[t] += tmp;
        __syncthreads();
    }
    if (i < NN) incl[i] = s[t];
    if (t == 255) bsum[blockIdx.x] = s[255];
}

__global__ __launch_bounds__(512)
void k_scan_top(const int* __restrict__ bsum, int* __restrict__ bscan) {
    __shared__ int s[512];
    int t = threadIdx.x;
    s[t] = (t < NB1) ? bsum[t] : 0;
    __syncthreads();
    #pragma unroll
    for (int off = 1; off < 512; off <<= 1) {
        int tmp = (t >= off) ? s[t - off] : 0;
        __syncthreads();
        s[t] += tmp;
        __syncthreads();
    }
    if (t < NB1) bscan[t] = s[t];
}

__global__ __launch_bounds__(256)
void k_scan_fix(const int* __restrict__ incl, const int* __restrict__ bscan,
                int* __restrict__ rowptr) {
    int i = blockIdx.x * 256 + threadIdx.x;
    if (i < NN) {
        int off = (blockIdx.x > 0) ? bscan[blockIdx.x - 1] : 0;
        rowptr[i + 1] = incl[i] + off;
        if (i == 0) rowptr[0] = 0;
    }
}

__global__ __launch_bounds__(256)
void k_scatter(const int* __restrict__ src, const int* __restrict__ dst,
               const int* __restrict__ rowptr, int* __restrict__ cursor,
               int* __restrict__ eidx) {
    int e = blockIdx.x * 256 + threadIdx.x;
    if (e < NE) {
        int d = dst[e];
        int pos = rowptr[d] + atomicAdd(cursor + d, 1);
        eidx[pos] = src[e];
    }
}

// ===========================================================================
// CSR aggregation, fused GIN prolog:  out[n] = (1+eps)*x[n] + sum_in x[src]
// One wave per node; lane owns F/64 consecutive floats.
// ===========================================================================
template<int F>
__global__ __launch_bounds__(64)
void k_aggr(const float* __restrict__ x, const int* __restrict__ rowptr,
            const int* __restrict__ eidx, const float* __restrict__ epsp,
            float* __restrict__ out) {
    const int n = blockIdx.x;
    const int t = threadIdx.x;
    const int p0 = rowptr[n], p1 = rowptr[n + 1];
    const float e1 = 1.0f + epsp[0];

    if constexpr (F == 128) {
        const long long base = (long long)t * 2;
        float2 a0 = make_float2(0.f, 0.f), a1 = make_float2(0.f, 0.f);
        int p = p0;
        for (; p + 1 < p1; p += 2) {
            int s0 = eidx[p], s1 = eidx[p + 1];
            float2 v0 = *reinterpret_cast<const float2*>(x + (long long)s0 * F + base);
            float2 v1 = *reinterpret_cast<const float2*>(x + (long long)s1 * F + base);
            a0.x += v0.x; a0.y += v0.y;
            a1.x += v1.x; a1.y += v1.y;
        }
        if (p < p1) {
            int s0 = eidx[p];
            float2 v0 = *reinterpret_cast<const float2*>(x + (long long)s0 * F + base);
            a0.x += v0.x; a0.y += v0.y;
        }
        float2 xs = *reinterpret_cast<const float2*>(x + (long long)n * F + base);
        float2 o;
        o.x = fmaf(e1, xs.x, a0.x + a1.x);
        o.y = fmaf(e1, xs.y, a0.y + a1.y);
        *reinterpret_cast<float2*>(out + (long long)n * F + base) = o;
    } else {  // F == 64
        float a0 = 0.f, a1 = 0.f;
        int p = p0;
        for (; p + 1 < p1; p += 2) {
            int s0 = eidx[p], s1 = eidx[p + 1];
            a0 += x[(long long)s0 * F + t];
            a1 += x[(long long)s1 * F + t];
        }
        if (p < p1) a0 += x[(long long)eidx[p] * F + t];
        float xs = x[(long long)n * F + t];
        out[(long long)n * F + t] = fmaf(e1, xs, a0 + a1);
    }
}

// ===========================================================================
// GEMM: C[N x 128] = Pro(A) @ W[K x 128] + bias, optional relu epilogue.
// PRO 0: A plain     PRO 1: relu(af*A + bf)  (BN+relu fused into A-load)
// EPI 0: none        EPI 1: relu
// Tile 128x128, 256 threads, 8x8 acc/thread.
// ===========================================================================
template<int K, int PRO, int EPI>
__global__ __launch_bounds__(256)
void k_gemm(const float* __restrict__ A,
            const float* __restrict__ af,
            const float* __restrict__ bf,
            const float* __restrict__ W,
            const float* __restrict__ bias,
            float* __restrict__ C) {
    constexpr int BM = 128, BN = 128, KC = 32;
    __shared__ float As[KC][BM + 4];
    __shared__ float Bs[KC][BN];

    const int t = threadIdx.x;
    const int rbase = blockIdx.x * BM;
    const int tx = t & 15, ty = t >> 4;
    const int col0 = tx * 8, row0 = ty * 8;

    float acc[8][8];
    #pragma unroll
    for (int i = 0; i < 8; ++i)
        #pragma unroll
        for (int j = 0; j < 8; ++j) acc[i][j] = 0.f;

    for (int kb = 0; kb < K; kb += KC) {
        #pragma unroll
        for (int i = 0; i < 4; ++i) {
            int q   = t * 4 + i;
            int row = q >> 3;
            int kq  = q & 7;
            int grow = rbase + row;
            float4 v = make_float4(0.f, 0.f, 0.f, 0.f);
            if (grow < NN) {
                long long gidx = (long long)grow * K + kb + kq * 4;
                v = *reinterpret_cast<const float4*>(A + gidx);
                if (PRO == 1) {
                    int kk = kb + kq * 4;
                    float4 a4 = *reinterpret_cast<const float4*>(af + kk);
                    float4 b4 = *reinterpret_cast<const float4*>(bf + kk);
                    v.x = fmaxf(fmaf(a4.x, v.x, b4.x), 0.f);
                    v.y = fmaxf(fmaf(a4.y, v.y, b4.y), 0.f);
                    v.z = fmaxf(fmaf(a4.z, v.z, b4.z), 0.f);
                    v.w = fmaxf(fmaf(a4.w, v.w, b4.w), 0.f);
                }
            }
            As[kq * 4 + 0][row] = v.x;
            As[kq * 4 + 1][row] = v.y;
            As[kq * 4 + 2][row] = v.z;
            As[kq * 4 + 3][row] = v.w;
        }
        #pragma unroll
        for (int i = 0; i < 4; ++i) {
            int q  = t * 4 + i;
            int k  = q >> 5;
            int c4 = q & 31;
            float4 w = *reinterpret_cast<const float4*>(W + (long long)(kb + k) * BN + c4 * 4);
            *reinterpret_cast<float4*>(&Bs[k][c4 * 4]) = w;
        }
        __syncthreads();

        #pragma unroll
        for (int k = 0; k < KC; ++k) {
            float a[8], b[8];
            *reinterpret_cast<float4*>(&a[0]) = *reinterpret_cast<const float4*>(&As[k][row0]);
            *reinterpret_cast<float4*>(&a[4]) = *reinterpret_cast<const float4*>(&As[k][row0 + 4]);
            *reinterpret_cast<float4*>(&b[0]) = *reinterpret_cast<const float4*>(&Bs[k][col0]);
            *reinterpret_cast<float4*>(&b[4]) = *reinterpret_cast<const float4*>(&Bs[k][col0 + 4]);
            #pragma unroll
            for (int i = 0; i < 8; ++i)
                #pragma unroll
                for (int j = 0; j < 8; ++j)
                    acc[i][j] = fmaf(a[i], b[j], acc[i][j]);
        }
        __syncthreads();
    }

    float bv[8];
    *reinterpret_cast<float4*>(&bv[0]) = *reinterpret_cast<const float4*>(bias + col0);
    *reinterpret_cast<float4*>(&bv[4]) = *reinterpret_cast<const float4*>(bias + col0 + 4);
    #pragma unroll
    for (int i = 0; i < 8; ++i) {
        int grow = rbase + row0 + i;
        if (grow < NN) {
            float o[8];
            #pragma unroll
            for (int j = 0; j < 8; ++j) {
                float v = acc[i][j] + bv[j];
                if (EPI == 1) v = fmaxf(v, 0.f);
                o[j] = v;
            }
            *reinterpret_cast<float4*>(C + (long long)grow * HD + col0)     = *reinterpret_cast<float4*>(&o[0]);
            *reinterpret_cast<float4*>(C + (long long)grow * HD + col0 + 4) = *reinterpret_cast<float4*>(&o[4]);
        }
    }
}

// ===========================================================================
// BN stats: column sum/sumsq in double, then fold into scale/shift.
// ===========================================================================
__global__ __launch_bounds__(128)
void k_colstats(const float* __restrict__ y, double* __restrict__ dsum,
                double* __restrict__ dsq, int rows_per_block) {
    int c  = threadIdx.x;
    int r0 = blockIdx.x * rows_per_block;
    int r1 = r0 + rows_per_block;
    if (r1 > NN) r1 = NN;
    double s = 0.0, sq = 0.0;
    for (int r = r0; r < r1; ++r) {
        float v = y[(long long)r * HD + c];
        s  += (double)v;
        sq += (double)v * (double)v;
    }
    atomicAdd(dsum + c, s);
    atomicAdd(dsq + c, sq);
}

__global__ __launch_bounds__(128)
void k_bnfin(const double* __restrict__ dsum, const double* __restrict__ dsq,
             const float* __restrict__ g, const float* __restrict__ be,
             float* __restrict__ af, float* __restrict__ bf) {
    int c = threadIdx.x;
    double mu  = dsum[c] / (double)NN;
    double var = dsq[c] / (double)NN - mu * mu;
    double a   = (double)g[c] / sqrt(var + 1e-5);
    af[c] = (float)a;
    bf[c] = be[c] - (float)(mu * a);
}

// ===========================================================================
// Head lin2: out[N x 2] = x[N x 128] @ w[128 x 2] + b
// ===========================================================================
__global__ __launch_bounds__(256)
void k_head2(const float* __restrict__ x, const float* __restrict__ w,
             const float* __restrict__ b, float* __restrict__ out) {
    __shared__ float ws[256];
    if (threadIdx.x < 256) ws[threadIdx.x] = w[threadIdx.x];
    __syncthreads();
    int r = blockIdx.x * blockDim.x + threadIdx.x;
    if (r >= NN) return;
    float a0 = b[0], a1 = b[1];
    const float4* xr = reinterpret_cast<const float4*>(x + (long long)r * HD);
    #pragma unroll
    for (int k4 = 0; k4 < 32; ++k4) {
        float4 v = xr[k4];
        int k = k4 * 4;
        a0 = fmaf(v.x, ws[(k + 0) * 2], a0);
        a0 = fmaf(v.y, ws[(k + 1) * 2], a0);
        a0 = fmaf(v.z, ws[(k + 2) * 2], a0);
        a0 = fmaf(v.w, ws[(k + 3) * 2], a0);
        a1 = fmaf(v.x, ws[(k + 0) * 2 + 1], a1);
        a1 = fmaf(v.y, ws[(k + 1) * 2 + 1], a1);
        a1 = fmaf(v.z, ws[(k + 2) * 2 + 1], a1);
        a1 = fmaf(v.w, ws[(k + 3) * 2 + 1], a1);
    }
    out[r * 2 + 0] = a0;
    out[r * 2 + 1] = a1;
}

// ===========================================================================
extern "C" void kernel_launch(void* const* d_in, const int* in_sizes, int n_in,
                              void* d_out, int out_size, void* d_ws, size_t ws_size,
                              hipStream_t stream) {
    const float* x  = (const float*)d_in[0];
    const int*   ei = (const int*)d_in[1];
    const int* src = ei;
    const int* dst = ei + NE;
    auto P = [&](int i) { return (const float*)d_in[i]; };

    const size_t BUF = (size_t)NN * HD * sizeof(float);   // 51.2 MB
    char* ws = (char*)d_ws;
    float* B0 = (float*)(ws);
    float* B1 = (float*)(ws + BUF);
    float* B2 = (float*)(ws + 2 * BUF);
    char*  sb = ws + 3 * BUF;
    double* dsum = (double*)(sb);
    double* dsq  = (double*)(sb + 1024);
    float*  af   = (float*)(sb + 2048);
    float*  bf   = (float*)(sb + 2048 + 512);
    int* csr     = (int*)(sb + 4096);
    int* degree = csr;
    int* cursor = degree + NN;
    int* incl   = cursor + NN;
    int* bsum   = incl + NN;
    int* bscan  = bsum + 512;
    int* rowptr = bscan + 512;
    int* eidx   = rowptr + NN + 2;

    const int GEMM_GRID = (NN + 127) / 128;
    const int EGRID = (NE + 255) / 256;
    const int STAT_GRID = 512;
    const int STAT_ROWS = (NN + STAT_GRID - 1) / STAT_GRID;

    // ---- build CSR (dst-sorted) ----
    hipMemsetAsync(degree, 0, 2 * NN * sizeof(int), stream);   // degree + cursor
    k_hist<<<EGRID, 256, 0, stream>>>(dst, degree);
    k_scan_blk<<<NB1, 256, 0, stream>>>(degree, incl, bsum);
    k_scan_top<<<1, 512, 0, stream>>>(bsum, bscan);
    k_scan_fix<<<NB1, 256, 0, stream>>>(incl, bscan, rowptr);
    k_scatter<<<EGRID, 256, 0, stream>>>(src, dst, rowptr, cursor, eidx);

    auto bn = [&](const float* g, const float* be, const float* y) {
        hipMemsetAsync(dsum, 0, 2048, stream);
        k_colstats<<<STAT_GRID, 128, 0, stream>>>(y, dsum, dsq, STAT_ROWS);
        k_bnfin<<<1, 128, 0, stream>>>(dsum, dsq, g, be, af, bf);
    };

    // ---- layer 0 (K = 64) ----
    k_aggr<64><<<NN, 64, 0, stream>>>(x, rowptr, eidx, P(8), B0);
    k_gemm<64, 0, 0><<<GEMM_GRID, 256, 0, stream>>>(B0, nullptr, nullptr, P(2), P(3), B1);
    bn(P(4), P(5), B1);
    k_gemm<128, 1, 1><<<GEMM_GRID, 256, 0, stream>>>(B1, af, bf, P(6), P(7), B2);

    // ---- layer 1 ----
    k_aggr<128><<<NN, 64, 0, stream>>>(B2, rowptr, eidx, P(15), B0);
    k_gemm<128, 0, 0><<<GEMM_GRID, 256, 0, stream>>>(B0, nullptr, nullptr, P(9), P(10), B1);
    bn(P(11), P(12), B1);
    k_gemm<128, 1, 1><<<GEMM_GRID, 256, 0, stream>>>(B1, af, bf, P(13), P(14), B0);

    // ---- layer 2 ----
    k_aggr<128><<<NN, 64, 0, stream>>>(B0, rowptr, eidx, P(22), B2);
    k_gemm<128, 0, 0><<<GEMM_GRID, 256, 0, stream>>>(B2, nullptr, nullptr, P(16), P(17), B1);
    bn(P(18), P(19), B1);
    k_gemm<128, 1, 1><<<GEMM_GRID, 256, 0, stream>>>(B1, af, bf, P(20), P(21), B0);

    // ---- head ----
    k_gemm<128, 0, 1><<<GEMM_GRID, 256, 0, stream>>>(B0, nullptr, nullptr, P(23), P(24), B1);
    k_head2<<<(NN + 255) / 256, 256, 0, stream>>>(B1, P(25), P(26), (float*)d_out);
}

// Round 6
// 1021.304 us; speedup vs baseline: 7.3302x; 1.1798x over previous
//
#include <hip/hip_runtime.h>

#define NN 100000      // nodes
#define NE 1600000     // edges
#define HD 128         // hidden dim
#define NB1 391        // ceil(NN/256) scan blocks

typedef unsigned short u16;
typedef __attribute__((ext_vector_type(8))) short bf16x8;
typedef __attribute__((ext_vector_type(4))) float f32x4;

__device__ __forceinline__ u16 f2b(float f) {            // fp32 -> bf16 RNE
    unsigned u = __builtin_bit_cast(unsigned, f);
    unsigned r = (u + 0x7FFFu + ((u >> 16) & 1u)) >> 16;
    return (u16)r;
}
__device__ __forceinline__ float b2f(u16 h) {
    unsigned u = ((unsigned)h) << 16;
    return __builtin_bit_cast(float, u);
}
__device__ __forceinline__ float lof(unsigned v) {
    return __builtin_bit_cast(float, v << 16);
}
__device__ __forceinline__ float hif(unsigned v) {
    return __builtin_bit_cast(float, v & 0xFFFF0000u);
}
__device__ __forceinline__ unsigned pack2(float a, float b) {
    return (unsigned)f2b(a) | ((unsigned)f2b(b) << 16);
}

// ===========================================================================
// CSR build: degree histogram -> exclusive scan (rowptr) -> scatter src by dst
// ===========================================================================
__global__ __launch_bounds__(256)
void k_hist(const int* __restrict__ dst, int* __restrict__ degree) {
    int e = blockIdx.x * 256 + threadIdx.x;
    if (e < NE) atomicAdd(degree + dst[e], 1);
}

__global__ __launch_bounds__(256)
void k_scan_blk(const int* __restrict__ degree, int* __restrict__ incl,
                int* __restrict__ bsum) {
    __shared__ int s[256];
    int t = threadIdx.x;
    int i = blockIdx.x * 256 + t;
    int v = (i < NN) ? degree[i] : 0;
    s[t] = v;
    __syncthreads();
    #pragma unroll
    for (int off = 1; off < 256; off <<= 1) {
        int tmp = (t >= off) ? s[t - off] : 0;
        __syncthreads();
        s[t] += tmp;
        __syncthreads();
    }
    if (i < NN) incl[i] = s[t];
    if (t == 255) bsum[blockIdx.x] = s[255];
}

__global__ __launch_bounds__(512)
void k_scan_top(const int* __restrict__ bsum, int* __restrict__ bscan) {
    __shared__ int s[512];
    int t = threadIdx.x;
    s[t] = (t < NB1) ? bsum[t] : 0;
    __syncthreads();
    #pragma unroll
    for (int off = 1; off < 512; off <<= 1) {
        int tmp = (t >= off) ? s[t - off] : 0;
        __syncthreads();
        s[t] += tmp;
        __syncthreads();
    }
    if (t < NB1) bscan[t] = s[t];
}

__global__ __launch_bounds__(256)
void k_scan_fix(const int* __restrict__ incl, const int* __restrict__ bscan,
                int* __restrict__ rowptr) {
    int i = blockIdx.x * 256 + threadIdx.x;
    if (i < NN) {
        int off = (blockIdx.x > 0) ? bscan[blockIdx.x - 1] : 0;
        rowptr[i + 1] = incl[i] + off;
        if (i == 0) rowptr[0] = 0;
    }
}

__global__ __launch_bounds__(256)
void k_scatter(const int* __restrict__ src, const int* __restrict__ dst,
               const int* __restrict__ rowptr, int* __restrict__ cursor,
               int* __restrict__ eidx) {
    int e = blockIdx.x * 256 + threadIdx.x;
    if (e < NE) {
        int d = dst[e];
        int pos = rowptr[d] + atomicAdd(cursor + d, 1);
        eidx[pos] = src[e];
    }
}

// ===========================================================================
// x (fp32) -> bf16
// ===========================================================================
__global__ __launch_bounds__(256)
void k_cvt(const float* __restrict__ in, u16* __restrict__ out, int n4) {
    for (int i = blockIdx.x * 256 + threadIdx.x; i < n4; i += gridDim.x * 256) {
        float4 v = reinterpret_cast<const float4*>(in)[i];
        uint2 o;
        o.x = pack2(v.x, v.y);
        o.y = pack2(v.z, v.w);
        *reinterpret_cast<uint2*>(out + (size_t)i * 4) = o;
    }
}

// ===========================================================================
// CSR aggregation: bf16 gather in, fp32 accumulate, fp32 out.
//   out[n] = (1+eps)*x[n] + sum_{src in N(n)} x[src]
// One wave per node.
// ===========================================================================
template<int F>
__global__ __launch_bounds__(64)
void k_aggr(const u16* __restrict__ x, const int* __restrict__ rowptr,
            const int* __restrict__ eidx, const float* __restrict__ epsp,
            float* __restrict__ out) {
    const int n = blockIdx.x;
    const int t = threadIdx.x;
    const int p0 = rowptr[n], p1 = rowptr[n + 1];
    const float e1 = 1.0f + epsp[0];

    if constexpr (F == 128) {
        const unsigned off = 2u * t;
        float a0 = 0.f, a1 = 0.f, c0 = 0.f, c1 = 0.f;
        int p = p0;
        for (; p + 1 < p1; p += 2) {
            unsigned v0 = *reinterpret_cast<const unsigned*>(x + (size_t)eidx[p] * 128 + off);
            unsigned v1 = *reinterpret_cast<const unsigned*>(x + (size_t)eidx[p + 1] * 128 + off);
            a0 += lof(v0); a1 += hif(v0);
            c0 += lof(v1); c1 += hif(v1);
        }
        if (p < p1) {
            unsigned v0 = *reinterpret_cast<const unsigned*>(x + (size_t)eidx[p] * 128 + off);
            a0 += lof(v0); a1 += hif(v0);
        }
        unsigned xs = *reinterpret_cast<const unsigned*>(x + (size_t)n * 128 + off);
        float2 o;
        o.x = fmaf(e1, lof(xs), a0 + c0);
        o.y = fmaf(e1, hif(xs), a1 + c1);
        *reinterpret_cast<float2*>(out + (size_t)n * 128 + off) = o;
    } else {  // F == 64, one bf16 per lane
        float a0 = 0.f, a1 = 0.f;
        int p = p0;
        for (; p + 1 < p1; p += 2) {
            a0 += b2f(x[(size_t)eidx[p] * 64 + t]);
            a1 += b2f(x[(size_t)eidx[p + 1] * 64 + t]);
        }
        if (p < p1) a0 += b2f(x[(size_t)eidx[p] * 64 + t]);
        float xs = b2f(x[(size_t)n * 64 + t]);
        out[(size_t)n * 64 + t] = fmaf(e1, xs, a0 + a1);
    }
}

// ===========================================================================
// Split-bf16 MFMA GEMM (fp32-accurate): C[N x 128] = Pro(A[N x K]) @ W + bias
// A fp32, W fp32. Each value split hi=bf16(v), lo=bf16(v-hi); product via
// 3 MFMAs (hi*hi + lo_w*hi_a + hi_w*lo_a); residual ~1.6e-5 relative.
// Swapped operands: D = mfma(W_frag, feat_frag); thread l holds
//   C[m = mbase+mb*16+(l&15)][n = nb*16+(l>>4)*4+r]
// W staged in LDS as [n][K] hi/lo bf16, XOR-swizzled.
// PRO 1: feat := relu(af*feat + bf) in fp32 (BN fused).  EPI 1: relu.
// OUTBF 1: bf16 out (gather buffer), else fp32 out.
// ===========================================================================
template<int K, int PRO, int EPI, int OUTBF>
__global__ __launch_bounds__(256)
void k_gemm(const float* __restrict__ A,
            const float* __restrict__ af,
            const float* __restrict__ bff,
            const float* __restrict__ W,
            const float* __restrict__ bias,
            void* __restrict__ Cout) {
    __shared__ u16 Whi[128 * K];
    __shared__ u16 Wlo[128 * K];

    const int t = threadIdx.x;
    const int l = t & 63;
    const int w = t >> 6;
    const int mbase = blockIdx.x * 128 + w * 32;
    const int l15 = l & 15;
    const int lg = l >> 4;           // 0..3

    // ---- stage W -> hi/lo bf16 [n][K], swizzled ----
    for (int idx = t; idx < K * 32; idx += 256) {
        int k  = idx >> 5;
        int n0 = (idx & 31) * 4;
        float4 wv = *reinterpret_cast<const float4*>(W + (size_t)k * 128 + n0);
        float wa[4] = {wv.x, wv.y, wv.z, wv.w};
        #pragma unroll
        for (int j = 0; j < 4; ++j) {
            int n = n0 + j;
            int byte = n * (2 * K) + k * 2;
            byte ^= ((n & 7) << 4);
            u16 hi = f2b(wa[j]);
            u16 lo = f2b(wa[j] - b2f(hi));
            *reinterpret_cast<u16*>(reinterpret_cast<char*>(Whi) + byte) = hi;
            *reinterpret_cast<u16*>(reinterpret_cast<char*>(Wlo) + byte) = lo;
        }
    }
    __syncthreads();

    f32x4 acc[2][8];
    #pragma unroll
    for (int i = 0; i < 2; ++i)
        #pragma unroll
        for (int j = 0; j < 8; ++j) acc[i][j] = (f32x4){0.f, 0.f, 0.f, 0.f};

    #pragma unroll
    for (int kc = 0; kc < K / 32; ++kc) {
        // W fragments (hi+lo) for this k-chunk
        bf16x8 whi[8], wlo[8];
        #pragma unroll
        for (int nb = 0; nb < 8; ++nb) {
            int n = nb * 16 + l15;
            int byte = n * (2 * K) + kc * 64 + lg * 16;
            byte ^= ((n & 7) << 4);
            whi[nb] = *reinterpret_cast<const bf16x8*>(
                reinterpret_cast<const char*>(Whi) + byte);
            wlo[nb] = *reinterpret_cast<const bf16x8*>(
                reinterpret_cast<const char*>(Wlo) + byte);
        }
        float aa[8], bb[8];
        if (PRO == 1) {
            int kk = kc * 32 + lg * 8;
            float4 x0 = *reinterpret_cast<const float4*>(af + kk);
            float4 x1 = *reinterpret_cast<const float4*>(af + kk + 4);
            float4 y0 = *reinterpret_cast<const float4*>(bff + kk);
            float4 y1 = *reinterpret_cast<const float4*>(bff + kk + 4);
            aa[0] = x0.x; aa[1] = x0.y; aa[2] = x0.z; aa[3] = x0.w;
            aa[4] = x1.x; aa[5] = x1.y; aa[6] = x1.z; aa[7] = x1.w;
            bb[0] = y0.x; bb[1] = y0.y; bb[2] = y0.z; bb[3] = y0.w;
            bb[4] = y1.x; bb[5] = y1.y; bb[6] = y1.z; bb[7] = y1.w;
        }
        #pragma unroll
        for (int mb = 0; mb < 2; ++mb) {
            int m = mbase + mb * 16 + l15;
            float av[8] = {0.f, 0.f, 0.f, 0.f, 0.f, 0.f, 0.f, 0.f};
            if (m < NN) {
                const float* ap = A + (size_t)m * K + kc * 32 + lg * 8;
                float4 x0 = *reinterpret_cast<const float4*>(ap);
                float4 x1 = *reinterpret_cast<const float4*>(ap + 4);
                av[0] = x0.x; av[1] = x0.y; av[2] = x0.z; av[3] = x0.w;
                av[4] = x1.x; av[5] = x1.y; av[6] = x1.z; av[7] = x1.w;
            }
            if (PRO == 1) {
                #pragma unroll
                for (int j = 0; j < 8; ++j)
                    av[j] = fmaxf(fmaf(aa[j], av[j], bb[j]), 0.f);
            }
            union { bf16x8 v; u16 s[8]; } uh, ul;
            #pragma unroll
            for (int j = 0; j < 8; ++j) {
                u16 hi = f2b(av[j]);
                uh.s[j] = hi;
                ul.s[j] = f2b(av[j] - b2f(hi));
            }
            #pragma unroll
            for (int nb = 0; nb < 8; ++nb) {
                acc[mb][nb] = __builtin_amdgcn_mfma_f32_16x16x32_bf16(
                    whi[nb], uh.v, acc[mb][nb], 0, 0, 0);
                acc[mb][nb] = __builtin_amdgcn_mfma_f32_16x16x32_bf16(
                    whi[nb], ul.v, acc[mb][nb], 0, 0, 0);
                acc[mb][nb] = __builtin_amdgcn_mfma_f32_16x16x32_bf16(
                    wlo[nb], uh.v, acc[mb][nb], 0, 0, 0);
            }
        }
    }

    // ---- epilogue: bias (+relu), store ----
    #pragma unroll
    for (int nb = 0; nb < 8; ++nb) {
        int n0 = nb * 16 + lg * 4;
        float4 b4 = *reinterpret_cast<const float4*>(bias + n0);
        #pragma unroll
        for (int mb = 0; mb < 2; ++mb) {
            int m = mbase + mb * 16 + l15;
            if (m >= NN) continue;
            float v0 = acc[mb][nb][0] + b4.x;
            float v1 = acc[mb][nb][1] + b4.y;
            float v2 = acc[mb][nb][2] + b4.z;
            float v3 = acc[mb][nb][3] + b4.w;
            if (EPI == 1) {
                v0 = fmaxf(v0, 0.f); v1 = fmaxf(v1, 0.f);
                v2 = fmaxf(v2, 0.f); v3 = fmaxf(v3, 0.f);
            }
            if (OUTBF == 1) {
                uint2 o;
                o.x = pack2(v0, v1);
                o.y = pack2(v2, v3);
                *reinterpret_cast<uint2*>((u16*)Cout + (size_t)m * 128 + n0) = o;
            } else {
                float4 o = make_float4(v0, v1, v2, v3);
                *reinterpret_cast<float4*>((float*)Cout + (size_t)m * 128 + n0) = o;
            }
        }
    }
}

// ===========================================================================
// BN stats on fp32 y: column sum/sumsq in double -> fold to scale/shift.
// ===========================================================================
__global__ __launch_bounds__(128)
void k_colstats(const float* __restrict__ y, double* __restrict__ dsum,
                double* __restrict__ dsq, int rows_per_block) {
    int c  = threadIdx.x;
    int r0 = blockIdx.x * rows_per_block;
    int r1 = r0 + rows_per_block;
    if (r1 > NN) r1 = NN;
    double s = 0.0, sq = 0.0;
    for (int r = r0; r < r1; ++r) {
        float v = y[(size_t)r * HD + c];
        s  += (double)v;
        sq += (double)v * (double)v;
    }
    atomicAdd(dsum + c, s);
    atomicAdd(dsq + c, sq);
}

__global__ __launch_bounds__(128)
void k_bnfin(const double* __restrict__ dsum, const double* __restrict__ dsq,
             const float* __restrict__ g, const float* __restrict__ be,
             float* __restrict__ af, float* __restrict__ bf) {
    int c = threadIdx.x;
    double mu  = dsum[c] / (double)NN;
    double var = dsq[c] / (double)NN - mu * mu;
    double a   = (double)g[c] / sqrt(var + 1e-5);
    af[c] = (float)a;
    bf[c] = be[c] - (float)(mu * a);
}

// ===========================================================================
// Head lin2: out[N x 2] = x[N x 128](fp32) @ w[128 x 2] + b
// ===========================================================================
__global__ __launch_bounds__(256)
void k_head2(const float* __restrict__ x, const float* __restrict__ w,
             const float* __restrict__ b, float* __restrict__ out) {
    __shared__ float ws[256];
    ws[threadIdx.x] = w[threadIdx.x];
    __syncthreads();
    int r = blockIdx.x * blockDim.x + threadIdx.x;
    if (r >= NN) return;
    float a0 = b[0], a1 = b[1];
    const float4* xr = reinterpret_cast<const float4*>(x + (size_t)r * HD);
    #pragma unroll
    for (int k4 = 0; k4 < 32; ++k4) {
        float4 v = xr[k4];
        int k = k4 * 4;
        a0 = fmaf(v.x, ws[(k + 0) * 2], a0);
        a0 = fmaf(v.y, ws[(k + 1) * 2], a0);
        a0 = fmaf(v.z, ws[(k + 2) * 2], a0);
        a0 = fmaf(v.w, ws[(k + 3) * 2], a0);
        a1 = fmaf(v.x, ws[(k + 0) * 2 + 1], a1);
        a1 = fmaf(v.y, ws[(k + 1) * 2 + 1], a1);
        a1 = fmaf(v.z, ws[(k + 2) * 2 + 1], a1);
        a1 = fmaf(v.w, ws[(k + 3) * 2 + 1], a1);
    }
    out[r * 2 + 0] = a0;
    out[r * 2 + 1] = a1;
}

// ===========================================================================
extern "C" void kernel_launch(void* const* d_in, const int* in_sizes, int n_in,
                              void* d_out, int out_size, void* d_ws, size_t ws_size,
                              hipStream_t stream) {
    const float* x  = (const float*)d_in[0];
    const int*   ei = (const int*)d_in[1];
    const int* src = ei;
    const int* dst = ei + NE;
    auto P = [&](int i) { return (const float*)d_in[i]; };

    const size_t BUFF = (size_t)NN * HD * sizeof(float);  // 51.2 MB fp32
    const size_t BUFH = (size_t)NN * HD * sizeof(u16);    // 25.6 MB bf16
    char* ws = (char*)d_ws;
    float* aggF = (float*)(ws);                           // fp32 [NN][128]
    float* yF   = (float*)(ws + BUFF);                    // fp32 [NN][128]
    u16*   gB   = (u16*)(ws + 2 * BUFF);                  // bf16 [NN][128]
    u16*   xb   = (u16*)(ws + 2 * BUFF + BUFH);           // bf16 [NN][64]
    char*  sb   = ws + 2 * BUFF + BUFH + (size_t)NN * 64 * sizeof(u16);
    double* dsum = (double*)(sb);
    double* dsq  = (double*)(sb + 1024);
    float*  af   = (float*)(sb + 2048);
    float*  bf   = (float*)(sb + 2048 + 512);
    int* degree = (int*)(sb + 4096);
    int* cursor = degree + NN;
    int* incl   = cursor + NN;
    int* bsum   = incl + NN;
    int* bscan  = bsum + 512;
    int* rowptr = bscan + 512;
    int* eidx   = rowptr + NN + 2;

    const int GEMM_GRID = (NN + 127) / 128;               // 782
    const int EGRID = (NE + 255) / 256;

    // ---- build CSR (dst-sorted) ----
    hipMemsetAsync(degree, 0, 2 * NN * sizeof(int), stream);
    k_hist<<<EGRID, 256, 0, stream>>>(dst, degree);
    k_scan_blk<<<NB1, 256, 0, stream>>>(degree, incl, bsum);
    k_scan_top<<<1, 512, 0, stream>>>(bsum, bscan);
    k_scan_fix<<<NB1, 256, 0, stream>>>(incl, bscan, rowptr);
    k_scatter<<<EGRID, 256, 0, stream>>>(src, dst, rowptr, cursor, eidx);

    const int STAT_GRID = 512;
    const int STAT_ROWS = (NN + STAT_GRID - 1) / STAT_GRID;
    auto bn = [&](const float* g, const float* be, const float* y) {
        hipMemsetAsync(dsum, 0, 2048, stream);
        k_colstats<<<STAT_GRID, 128, 0, stream>>>(y, dsum, dsq, STAT_ROWS);
        k_bnfin<<<1, 128, 0, stream>>>(dsum, dsq, g, be, af, bf);
    };

    // ---- x -> bf16 ----
    k_cvt<<<2048, 256, 0, stream>>>(x, xb, NN * 64 / 4);

    // ---- layer 0 (K = 64) ----
    k_aggr<64><<<NN, 64, 0, stream>>>(xb, rowptr, eidx, P(8), aggF);
    k_gemm<64, 0, 0, 0><<<GEMM_GRID, 256, 0, stream>>>(aggF, nullptr, nullptr, P(2), P(3), yF);
    bn(P(4), P(5), yF);
    k_gemm<128, 1, 1, 1><<<GEMM_GRID, 256, 0, stream>>>(yF, af, bf, P(6), P(7), gB);

    // ---- layer 1 ----
    k_aggr<128><<<NN, 64, 0, stream>>>(gB, rowptr, eidx, P(15), aggF);
    k_gemm<128, 0, 0, 0><<<GEMM_GRID, 256, 0, stream>>>(aggF, nullptr, nullptr, P(9), P(10), yF);
    bn(P(11), P(12), yF);
    k_gemm<128, 1, 1, 1><<<GEMM_GRID, 256, 0, stream>>>(yF, af, bf, P(13), P(14), gB);

    // ---- layer 2 ----
    k_aggr<128><<<NN, 64, 0, stream>>>(gB, rowptr, eidx, P(22), aggF);
    k_gemm<128, 0, 0, 0><<<GEMM_GRID, 256, 0, stream>>>(aggF, nullptr, nullptr, P(16), P(17), yF);
    bn(P(18), P(19), yF);
    k_gemm<128, 1, 1, 0><<<GEMM_GRID, 256, 0, stream>>>(yF, af, bf, P(20), P(21), aggF);  // fp32 out

    // ---- head ----
    k_gemm<128, 0, 1, 0><<<GEMM_GRID, 256, 0, stream>>>(aggF, nullptr, nullptr, P(23), P(24), yF);
    k_head2<<<(NN + 255) / 256, 256, 0, stream>>>(yF, P(25), P(26), (float*)d_out);
}